// Round 6
// baseline (356.487 us; speedup 1.0000x reference)
//
#include <hip/hip_runtime.h>

#define NN 50000
#define EE 500000
#define DD 64
#define GG 50
#define NPG 1000

#define EMB_BLOCKS ((NN * DD + 255) / 256)   // 12500
#define HIST_BLOCKS ((EE + 255) / 256)       // 1954
#define UPD_BLOCKS ((NN + 63) / 64)          // 782

// ---------------------------------------------------------------- embed + hist
__global__ __launch_bounds__(256) void k_embed_hist(const float* __restrict__ hin,
                                                    const float* __restrict__ Wemb,
                                                    const float* __restrict__ bemb,
                                                    float* __restrict__ h,
                                                    const int* __restrict__ dst,
                                                    int* __restrict__ counts) {
    __shared__ float sW[5 * DD];
    __shared__ float sb[DD];
    int t = threadIdx.x;
    if (blockIdx.x < EMB_BLOCKS) {
        for (int i = t; i < 5 * DD; i += 256) sW[i] = Wemb[i];
        if (t < DD) sb[t] = bemb[t];
        __syncthreads();
        int idx = blockIdx.x * 256 + t;
        if (idx >= NN * DD) return;
        int n = idx >> 6, d = idx & 63;
        const float* row = hin + n * 5;
        float acc = sb[d];
#pragma unroll
        for (int k = 0; k < 5; ++k) acc = fmaf(row[k], sW[k * DD + d], acc);
        h[idx] = fmaxf(acc, 0.f);
    } else {
        int e = (blockIdx.x - EMB_BLOCKS) * 256 + t;
        if (e < EE) atomicAdd(&counts[dst[e]], 1);
    }
}

// ---------------------------------------------------------------- scan (single block)
__global__ __launch_bounds__(1024) void k_scan(const int* __restrict__ counts,
                                               int* __restrict__ row_ptr) {
    __shared__ int swave[16];
    __shared__ int sbase;
    int t = threadIdx.x;
    int lane = t & 63, wv = t >> 6;
    if (t == 0) { sbase = 0; row_ptr[0] = 0; }
    __syncthreads();
    for (int chunk = 0; chunk < NN; chunk += 4096) {
        int i0 = chunk + t * 4;
        int v[4];
#pragma unroll
        for (int j = 0; j < 4; ++j) {
            int i = i0 + j;
            v[j] = (i < NN) ? counts[i] : 0;
        }
        int tsum = v[0] + v[1] + v[2] + v[3];
        int x = tsum;
#pragma unroll
        for (int off = 1; off < 64; off <<= 1) {
            int y = __shfl_up(x, off);
            if (lane >= off) x += y;
        }
        if (lane == 63) swave[wv] = x;
        __syncthreads();
        if (wv == 0 && lane < 16) {
            int w = swave[lane];
#pragma unroll
            for (int off = 1; off < 16; off <<= 1) {
                int y = __shfl_up(w, off);
                if (lane >= off) w += y;
            }
            swave[lane] = w;
        }
        __syncthreads();
        int wbase = (wv == 0) ? 0 : swave[wv - 1];
        int run = x - tsum + wbase + sbase;
#pragma unroll
        for (int j = 0; j < 4; ++j) {
            run += v[j];
            int i = i0 + j;
            if (i < NN) row_ptr[i + 1] = run;
        }
        __syncthreads();
        if (t == 0) sbase += swave[15];
        __syncthreads();
    }
}

// ---------------------------------------------------------------- scatter
__global__ __launch_bounds__(256) void k_scatter(const int* __restrict__ src,
                                                 const int* __restrict__ dst,
                                                 const float* __restrict__ pos,
                                                 const int* __restrict__ row_ptr,
                                                 int* __restrict__ cursor,
                                                 int2* __restrict__ ep) {
    int e = blockIdx.x * 256 + threadIdx.x;
    if (e >= EE) return;
    int j = src[e], i = dst[e];
    int p = row_ptr[i] + atomicAdd(&cursor[i], 1);
    float dx = pos[2 * i] - pos[2 * j];
    float dy = pos[2 * i + 1] - pos[2 * j + 1];
    float dist = sqrtf(dx * dx + dy * dy);
    ep[p] = make_int2(j, __float_as_int(dist));
}

// ---------------------------------------------------------------- helpers
__device__ __forceinline__ float f4c(const float4& v, int kk) {
    switch (kk) {
        case 0: return v.x;
        case 1: return v.y;
        case 2: return v.z;
        default: return v.w;
    }
}

// ---------------------------------------------------------------- A/B GEMM (+ optional fused PairNorm on input)
template <bool NORM>
__global__ __launch_bounds__(256) void k_ab(const float* __restrict__ X,
                                            const float* __restrict__ gmu,
                                            const float* __restrict__ Wm,   // 129x64
                                            const float* __restrict__ bm,   // 64
                                            float* __restrict__ A,
                                            float* __restrict__ Bm) {
    __shared__ float sW[64 * 128];  // [k][c]
    __shared__ float sX[64 * 68];   // [r][k]
    const int tid = threadIdx.x;
    const int n0 = blockIdx.x * 64;

    for (int i4 = tid; i4 < 64 * 32; i4 += 256) {
        int k = i4 >> 5, cq = i4 & 31;
        float4 v = (cq < 16) ? ((const float4*)(Wm + k * 64))[cq]
                             : ((const float4*)(Wm + (64 + k) * 64))[cq - 16];
        ((float4*)sW)[i4] = v;
    }
    for (int i4 = tid; i4 < 64 * 16; i4 += 256) {
        int r = i4 >> 4, kq = i4 & 15;
        int n = n0 + r;
        float4 v = make_float4(0.f, 0.f, 0.f, 0.f);
        if (n < NN) v = *(const float4*)(X + n * DD + kq * 4);
        if (NORM) {
            float4 mu4 = *(const float4*)(gmu + kq * 4);
            float inv = gmu[64];
            v.x = (v.x - mu4.x) * inv;
            v.y = (v.y - mu4.y) * inv;
            v.z = (v.z - mu4.z) * inv;
            v.w = (v.w - mu4.w) * inv;
        }
        *(float4*)(&sX[r * 68 + kq * 4]) = v;
    }
    __syncthreads();

    const int rg = tid >> 4;
    const int cg = tid & 15;
    const int c0 = cg * 8;
    float acc[4][8];
#pragma unroll
    for (int cj = 0; cj < 8; ++cj) {
        float b = (c0 < 64) ? bm[c0 + cj] : 0.f;
        acc[0][cj] = b; acc[1][cj] = b; acc[2][cj] = b; acc[3][cj] = b;
    }
#pragma unroll 4
    for (int kq = 0; kq < 16; ++kq) {
        float4 x0 = *(const float4*)(&sX[(rg * 4 + 0) * 68 + kq * 4]);
        float4 x1 = *(const float4*)(&sX[(rg * 4 + 1) * 68 + kq * 4]);
        float4 x2 = *(const float4*)(&sX[(rg * 4 + 2) * 68 + kq * 4]);
        float4 x3 = *(const float4*)(&sX[(rg * 4 + 3) * 68 + kq * 4]);
#pragma unroll
        for (int kk = 0; kk < 4; ++kk) {
            const float* wr = &sW[(kq * 4 + kk) * 128 + c0];
            float4 w0 = *(const float4*)wr;
            float4 w1 = *(const float4*)(wr + 4);
            float wv[8] = {w0.x, w0.y, w0.z, w0.w, w1.x, w1.y, w1.z, w1.w};
            float a0 = f4c(x0, kk), a1 = f4c(x1, kk), a2 = f4c(x2, kk), a3 = f4c(x3, kk);
#pragma unroll
            for (int cj = 0; cj < 8; ++cj) {
                acc[0][cj] = fmaf(a0, wv[cj], acc[0][cj]);
                acc[1][cj] = fmaf(a1, wv[cj], acc[1][cj]);
                acc[2][cj] = fmaf(a2, wv[cj], acc[2][cj]);
                acc[3][cj] = fmaf(a3, wv[cj], acc[3][cj]);
            }
        }
    }
#pragma unroll
    for (int ri = 0; ri < 4; ++ri) {
        int n = n0 + rg * 4 + ri;
        if (n >= NN) continue;
        float4 o0 = make_float4(acc[ri][0], acc[ri][1], acc[ri][2], acc[ri][3]);
        float4 o1 = make_float4(acc[ri][4], acc[ri][5], acc[ri][6], acc[ri][7]);
        if (c0 < 64) {
            *(float4*)(A + n * DD + c0) = o0;
            *(float4*)(A + n * DD + c0 + 4) = o1;
        } else {
            *(float4*)(Bm + n * DD + (c0 - 64)) = o0;
            *(float4*)(Bm + n * DD + (c0 - 64) + 4) = o1;
        }
    }
}

// ---------------------------------------------------------------- fused edge-aggregate + update GEMM + partials
// R6: phase 1 — 4 waves x 16 nodes gather-aggregate DIRECTLY into the sX GEMM
// operand (kills the aggr global round-trip + 1 dispatch/layer); 8-deep gather
// ILP. phase 2 — GEMM over [ag | X] exactly as old k_upd. hraw may alias A
// (blocks touch disjoint rows; A read precedes hraw write within a block).
template <bool NORM>
__global__ __launch_bounds__(256) void k_edge_upd(const float* __restrict__ X,
                                                  const float* __restrict__ gmu,
                                                  const float* __restrict__ A,
                                                  const float* __restrict__ B,
                                                  const float* __restrict__ w128,
                                                  const int* __restrict__ row_ptr,
                                                  const int2* __restrict__ ep,
                                                  const float* __restrict__ Wu,  // 128x64
                                                  const float* __restrict__ bu,  // 64
                                                  float* __restrict__ hraw,
                                                  float* __restrict__ part) {
    __shared__ float sW[64 * 64];
    __shared__ float sX[64 * 68];
    const int tid = threadIdx.x;
    const int n0 = blockIdx.x * 64;
    const int wv = tid >> 6, lane = tid & 63;

    // stage aggr-half weights (Wu rows 64..127) up front
    for (int i4 = tid; i4 < 64 * 16; i4 += 256)
        ((float4*)sW)[i4] = ((const float4*)(Wu + 64 * 64))[i4];

    // ---- phase 1: aggregation into sX (wave wv owns rows wv*16..wv*16+15)
    float w = w128[lane];
    for (int s = 0; s < 16; ++s) {
        int r = wv * 16 + s;
        int i = n0 + r;
        float a0 = 0.f, a1 = 0.f, a2 = 0.f, a3 = 0.f;
        if (i < NN) {
            float a = A[(size_t)i * DD + lane];
            int p0 = row_ptr[i], p1 = row_ptr[i + 1];
            int p = p0;
            for (; p + 8 <= p1; p += 8) {
                int4 e01 = *(const int4*)(&ep[p]);
                int4 e23 = *(const int4*)(&ep[p + 2]);
                int4 e45 = *(const int4*)(&ep[p + 4]);
                int4 e67 = *(const int4*)(&ep[p + 6]);
                float v0 = B[(size_t)e01.x * DD + lane];
                float v1 = B[(size_t)e01.z * DD + lane];
                float v2 = B[(size_t)e23.x * DD + lane];
                float v3 = B[(size_t)e23.z * DD + lane];
                float v4 = B[(size_t)e45.x * DD + lane];
                float v5 = B[(size_t)e45.z * DD + lane];
                float v6 = B[(size_t)e67.x * DD + lane];
                float v7 = B[(size_t)e67.z * DD + lane];
                a0 += fmaxf(fmaf(__int_as_float(e01.y), w, a) + v0, 0.f);
                a1 += fmaxf(fmaf(__int_as_float(e01.w), w, a) + v1, 0.f);
                a2 += fmaxf(fmaf(__int_as_float(e23.y), w, a) + v2, 0.f);
                a3 += fmaxf(fmaf(__int_as_float(e23.w), w, a) + v3, 0.f);
                a0 += fmaxf(fmaf(__int_as_float(e45.y), w, a) + v4, 0.f);
                a1 += fmaxf(fmaf(__int_as_float(e45.w), w, a) + v5, 0.f);
                a2 += fmaxf(fmaf(__int_as_float(e67.y), w, a) + v6, 0.f);
                a3 += fmaxf(fmaf(__int_as_float(e67.w), w, a) + v7, 0.f);
            }
            for (; p + 4 <= p1; p += 4) {
                int4 e01 = *(const int4*)(&ep[p]);
                int4 e23 = *(const int4*)(&ep[p + 2]);
                float v0 = B[(size_t)e01.x * DD + lane];
                float v1 = B[(size_t)e01.z * DD + lane];
                float v2 = B[(size_t)e23.x * DD + lane];
                float v3 = B[(size_t)e23.z * DD + lane];
                a0 += fmaxf(fmaf(__int_as_float(e01.y), w, a) + v0, 0.f);
                a1 += fmaxf(fmaf(__int_as_float(e01.w), w, a) + v1, 0.f);
                a2 += fmaxf(fmaf(__int_as_float(e23.y), w, a) + v2, 0.f);
                a3 += fmaxf(fmaf(__int_as_float(e23.w), w, a) + v3, 0.f);
            }
            if (p < p1) {
                int pl = p1 - 1;
                int pb = min(p + 1, pl), pc = min(p + 2, pl);
                int2 e0 = ep[p], e1 = ep[pb], e2 = ep[pc];
                float v0 = B[(size_t)e0.x * DD + lane];
                float v1 = B[(size_t)e1.x * DD + lane];
                float v2 = B[(size_t)e2.x * DD + lane];
                float c0 = fmaxf(fmaf(__int_as_float(e0.y), w, a) + v0, 0.f);
                float c1 = fmaxf(fmaf(__int_as_float(e1.y), w, a) + v1, 0.f);
                float c2 = fmaxf(fmaf(__int_as_float(e2.y), w, a) + v2, 0.f);
                a0 += c0;
                a1 += (p + 1 < p1) ? c1 : 0.f;
                a2 += (p + 2 < p1) ? c2 : 0.f;
            }
        }
        sX[r * 68 + lane] = (a0 + a1) + (a2 + a3);
    }
    __syncthreads();

    // ---- phase 2: GEMM. half A = aggregation (already in sX), half B = X.
    const int rg = tid >> 4;
    const int cg = tid & 15;
    const int c0 = cg * 4;
    float acc[4][4];
#pragma unroll
    for (int cj = 0; cj < 4; ++cj) {
        float b = bu[c0 + cj];
        acc[0][cj] = b; acc[1][cj] = b; acc[2][cj] = b; acc[3][cj] = b;
    }
#pragma unroll 1
    for (int half = 0; half < 2; ++half) {
        if (half) {
            __syncthreads();
            for (int i4 = tid; i4 < 64 * 16; i4 += 256)
                ((float4*)sW)[i4] = ((const float4*)Wu)[i4];
            for (int i4 = tid; i4 < 64 * 16; i4 += 256) {
                int r = i4 >> 4, kq = i4 & 15;
                int n = n0 + r;
                float4 v = make_float4(0.f, 0.f, 0.f, 0.f);
                if (n < NN) v = *(const float4*)(X + (size_t)n * DD + kq * 4);
                if (NORM) {
                    float4 mu4 = *(const float4*)(gmu + kq * 4);
                    float inv = gmu[64];
                    v.x = (v.x - mu4.x) * inv;
                    v.y = (v.y - mu4.y) * inv;
                    v.z = (v.z - mu4.z) * inv;
                    v.w = (v.w - mu4.w) * inv;
                }
                *(float4*)(&sX[r * 68 + kq * 4]) = v;
            }
            __syncthreads();
        }
#pragma unroll 4
        for (int kq = 0; kq < 16; ++kq) {
            float4 x0 = *(const float4*)(&sX[(rg * 4 + 0) * 68 + kq * 4]);
            float4 x1 = *(const float4*)(&sX[(rg * 4 + 1) * 68 + kq * 4]);
            float4 x2 = *(const float4*)(&sX[(rg * 4 + 2) * 68 + kq * 4]);
            float4 x3 = *(const float4*)(&sX[(rg * 4 + 3) * 68 + kq * 4]);
#pragma unroll
            for (int kk = 0; kk < 4; ++kk) {
                float4 wv4 = *(const float4*)(&sW[(kq * 4 + kk) * 64 + c0]);
                float wvv[4] = {wv4.x, wv4.y, wv4.z, wv4.w};
                float b0 = f4c(x0, kk), b1 = f4c(x1, kk), b2 = f4c(x2, kk), b3 = f4c(x3, kk);
#pragma unroll
                for (int cj = 0; cj < 4; ++cj) {
                    acc[0][cj] = fmaf(b0, wvv[cj], acc[0][cj]);
                    acc[1][cj] = fmaf(b1, wvv[cj], acc[1][cj]);
                    acc[2][cj] = fmaf(b2, wvv[cj], acc[2][cj]);
                    acc[3][cj] = fmaf(b3, wvv[cj], acc[3][cj]);
                }
            }
        }
    }
    // epilogue: relu, store, per-block partials (no atomics — R5)
    float lsq = 0.f;
    float4 csum = make_float4(0.f, 0.f, 0.f, 0.f);
#pragma unroll
    for (int ri = 0; ri < 4; ++ri) {
        int n = n0 + rg * 4 + ri;
        if (n >= NN) continue;
        float r0 = fmaxf(acc[ri][0], 0.f);
        float r1 = fmaxf(acc[ri][1], 0.f);
        float r2 = fmaxf(acc[ri][2], 0.f);
        float r3 = fmaxf(acc[ri][3], 0.f);
        *(float4*)(hraw + (size_t)n * DD + c0) = make_float4(r0, r1, r2, r3);
        lsq += r0 * r0 + r1 * r1 + r2 * r2 + r3 * r3;
        csum.x += r0; csum.y += r1; csum.z += r2; csum.w += r3;
    }
    __syncthreads();
    *(float4*)(&sX[rg * 68 + c0]) = csum;
#pragma unroll
    for (int off = 32; off > 0; off >>= 1) lsq += __shfl_down(lsq, off);
    if ((tid & 63) == 0) part[blockIdx.x * 68 + 64 + (tid >> 6)] = lsq;
    __syncthreads();
    if (tid < 64) {
        float s = 0.f;
#pragma unroll
        for (int rr = 0; rr < 16; ++rr) s += sX[rr * 68 + tid];
        part[blockIdx.x * 68 + tid] = s;
    }
}

// ---------------------------------------------------------------- pairnorm stats finalize (reduce partials)
__global__ __launch_bounds__(1024) void k_stats(const float* __restrict__ part,
                                                float* __restrict__ gmu) {
    __shared__ float scol[16][64];
    __shared__ float sq[16][4];
    __shared__ float sQ;
    int t = threadIdx.x;
    int d = t & 63, c = t >> 6;
    float s = 0.f, q = 0.f;
    for (int b = c; b < UPD_BLOCKS; b += 16) {
        s += part[b * 68 + d];
        if (d < 4) q += part[b * 68 + 64 + d];
    }
    scol[c][d] = s;
    if (d < 4) sq[c][d] = q;
    __syncthreads();
    if (t == 0) {
        float Q = 0.f;
#pragma unroll
        for (int cc = 0; cc < 16; ++cc)
            Q += sq[cc][0] + sq[cc][1] + sq[cc][2] + sq[cc][3];
        sQ = Q;
    }
    __syncthreads();
    if (t < 64) {
        float colsum = 0.f;
#pragma unroll
        for (int cc = 0; cc < 16; ++cc) colsum += scol[cc][t];
        float mu = colsum * (1.f / NN);
        gmu[t] = mu;
        float v = mu * mu;
#pragma unroll
        for (int off = 32; off > 0; off >>= 1) v += __shfl_down(v, off);
        if (t == 0) {
            float denom = sqrtf(1e-5f + sQ * (1.f / NN) - v);
            gmu[64] = 1.f / denom;
        }
    }
}

// ---------------------------------------------------------------- pool: 4 blocks/graph -> partial maxes
__global__ __launch_bounds__(256) void k_pool(const float* __restrict__ h,
                                              float* __restrict__ hg4) {
    __shared__ float sm[4][DD];
    int g = blockIdx.x >> 2, q = blockIdx.x & 3;
    int wv = threadIdx.x >> 6, lane = threadIdx.x & 63;
    int base = g * NPG + q * (NPG / 4);
    float m = -3.0e38f;
    for (int n = base + wv; n < base + NPG / 4; n += 4)
        m = fmaxf(m, h[(size_t)n * DD + lane]);
    sm[wv][lane] = m;
    __syncthreads();
    if (wv == 0) {
        m = fmaxf(fmaxf(sm[0][lane], sm[1][lane]), fmaxf(sm[2][lane], sm[3][lane]));
        hg4[(size_t)blockIdx.x * DD + lane] = m;
    }
}

// ---------------------------------------------------------------- head MLP (+ fused final norm: max commutes with positive affine)
__global__ __launch_bounds__(64) void k_head(const float* __restrict__ hg4,
                                             const float* __restrict__ gmu,
                                             const float* __restrict__ W1,
                                             const float* __restrict__ b1,
                                             const float* __restrict__ W2,
                                             const float* __restrict__ b2,
                                             float* __restrict__ out) {
    __shared__ float shg[DD];
    __shared__ float st[DD];
    int g = blockIdx.x, d = threadIdx.x;
    float m = fmaxf(fmaxf(hg4[(g * 4 + 0) * DD + d], hg4[(g * 4 + 1) * DD + d]),
                    fmaxf(hg4[(g * 4 + 2) * DD + d], hg4[(g * 4 + 3) * DD + d]));
    shg[d] = (m - gmu[d]) * gmu[64];
    __syncthreads();
    float acc = b1[d];
    for (int k = 0; k < DD; ++k) acc = fmaf(shg[k], W1[k * DD + d], acc);
    st[d] = fmaxf(acc, 0.f);
    __syncthreads();
    if (d < 2) {
        float o = b2[d];
        for (int k = 0; k < DD; ++k) o = fmaf(st[k], W2[k * 2 + d], o);
        out[g * 2 + d] = o;
    }
}

// ---------------------------------------------------------------- launch
extern "C" void kernel_launch(void* const* d_in, const int* in_sizes, int n_in,
                              void* d_out, int out_size, void* d_ws, size_t ws_size,
                              hipStream_t stream) {
    (void)in_sizes; (void)n_in; (void)out_size; (void)ws_size;
    const float* h_in = (const float*)d_in[0];
    const float* pos  = (const float*)d_in[1];
    const int*   eidx = (const int*)d_in[2];
    const float* Wemb = (const float*)d_in[4];
    const float* bemb = (const float*)d_in[5];
    const float* msgW = (const float*)d_in[6]; // 2 x 129 x 64
    const float* msgb = (const float*)d_in[7]; // 2 x 64
    const float* updW = (const float*)d_in[8]; // 2 x 128 x 64
    const float* updb = (const float*)d_in[9]; // 2 x 64
    const float* W1   = (const float*)d_in[10];
    const float* b1   = (const float*)d_in[11];
    const float* W2   = (const float*)d_in[12];
    const float* b2   = (const float*)d_in[13];
    float* out = (float*)d_out;

    float* hbuf    = (float*)d_ws;            // N*64
    float* Abuf    = hbuf + NN * DD;          // N*64
    float* Bbuf    = Abuf + NN * DD;          // N*64
    float* gmu0    = Bbuf + NN * DD;          // 66
    float* gmu1    = gmu0 + 66;               // 66
    float* hg4     = gmu1 + 66;               // 200*64 = 12800
    int2*  ep      = (int2*)(hg4 + 4 * GG * DD);  // E (offset even -> 8B aligned)
    int* counts    = (int*)(ep + EE);         // N   -- zeroed region start
    int* cursor    = counts + NN;             // N   -- zeroed region end
    int* row_ptr   = cursor + NN;             // N+1
    float* partials = (float*)(row_ptr + NN + 2); // UPD_BLOCKS*68

    const int* src = eidx;
    const int* dst = eidx + EE;

    hipMemsetAsync(counts, 0, 2 * NN * sizeof(int), stream);

    k_embed_hist<<<EMB_BLOCKS + HIST_BLOCKS, 256, 0, stream>>>(h_in, Wemb, bemb, hbuf,
                                                               dst, counts);
    k_scan<<<1, 1024, 0, stream>>>(counts, row_ptr);
    k_scatter<<<HIST_BLOCKS, 256, 0, stream>>>(src, dst, pos, row_ptr, cursor, ep);

    // ---- layer 0: h=hbuf -> A=Abuf,B=Bbuf -> hraw overwrites Abuf
    {
        const float* Wm = msgW;
        k_ab<false><<<UPD_BLOCKS, 256, 0, stream>>>(hbuf, nullptr, Wm, msgb,
                                                    Abuf, Bbuf);
        k_edge_upd<false><<<UPD_BLOCKS, 256, 0, stream>>>(hbuf, nullptr, Abuf, Bbuf,
                                                          Wm + 128 * DD, row_ptr, ep,
                                                          updW, updb, Abuf, partials);
        k_stats<<<1, 1024, 0, stream>>>(partials, gmu0);
    }
    // ---- layer 1: h=Abuf(+gmu0) -> A=hbuf,B=Bbuf -> hraw overwrites hbuf
    {
        const float* Wm = msgW + 129 * DD;
        k_ab<true><<<UPD_BLOCKS, 256, 0, stream>>>(Abuf, gmu0, Wm, msgb + DD,
                                                   hbuf, Bbuf);
        k_edge_upd<true><<<UPD_BLOCKS, 256, 0, stream>>>(Abuf, gmu0, hbuf, Bbuf,
                                                         Wm + 128 * DD, row_ptr, ep,
                                                         updW + 128 * DD, updb + DD,
                                                         hbuf, partials);
        k_stats<<<1, 1024, 0, stream>>>(partials, gmu1);
    }

    k_pool<<<4 * GG, 256, 0, stream>>>(hbuf, hg4);
    k_head<<<GG, 64, 0, stream>>>(hg4, gmu1, W1, b1, W2, b2, out);
}

// Round 7
// 345.034 us; speedup vs baseline: 1.0332x; 1.0332x over previous
//
#include <hip/hip_runtime.h>

#define NN 50000
#define EE 500000
#define DD 64
#define GG 50
#define NPG 1000

#define EMB_BLOCKS ((NN * DD + 255) / 256)   // 12500
#define HIST_BLOCKS ((EE + 255) / 256)       // 1954
#define UPD_BLOCKS ((NN + 63) / 64)          // 782

// ---------------------------------------------------------------- embed + hist
__global__ __launch_bounds__(256) void k_embed_hist(const float* __restrict__ hin,
                                                    const float* __restrict__ Wemb,
                                                    const float* __restrict__ bemb,
                                                    float* __restrict__ h,
                                                    const int* __restrict__ dst,
                                                    int* __restrict__ counts) {
    __shared__ float sW[5 * DD];
    __shared__ float sb[DD];
    int t = threadIdx.x;
    if (blockIdx.x < EMB_BLOCKS) {
        for (int i = t; i < 5 * DD; i += 256) sW[i] = Wemb[i];
        if (t < DD) sb[t] = bemb[t];
        __syncthreads();
        int idx = blockIdx.x * 256 + t;
        if (idx >= NN * DD) return;
        int n = idx >> 6, d = idx & 63;
        const float* row = hin + n * 5;
        float acc = sb[d];
#pragma unroll
        for (int k = 0; k < 5; ++k) acc = fmaf(row[k], sW[k * DD + d], acc);
        h[idx] = fmaxf(acc, 0.f);
    } else {
        int e = (blockIdx.x - EMB_BLOCKS) * 256 + t;
        if (e < EE) atomicAdd(&counts[dst[e]], 1);
    }
}

// ---------------------------------------------------------------- scan (single block)
__global__ __launch_bounds__(1024) void k_scan(const int* __restrict__ counts,
                                               int* __restrict__ row_ptr) {
    __shared__ int swave[16];
    __shared__ int sbase;
    int t = threadIdx.x;
    int lane = t & 63, wv = t >> 6;
    if (t == 0) { sbase = 0; row_ptr[0] = 0; }
    __syncthreads();
    for (int chunk = 0; chunk < NN; chunk += 4096) {
        int i0 = chunk + t * 4;
        int v[4];
#pragma unroll
        for (int j = 0; j < 4; ++j) {
            int i = i0 + j;
            v[j] = (i < NN) ? counts[i] : 0;
        }
        int tsum = v[0] + v[1] + v[2] + v[3];
        int x = tsum;
#pragma unroll
        for (int off = 1; off < 64; off <<= 1) {
            int y = __shfl_up(x, off);
            if (lane >= off) x += y;
        }
        if (lane == 63) swave[wv] = x;
        __syncthreads();
        if (wv == 0 && lane < 16) {
            int w = swave[lane];
#pragma unroll
            for (int off = 1; off < 16; off <<= 1) {
                int y = __shfl_up(w, off);
                if (lane >= off) w += y;
            }
            swave[lane] = w;
        }
        __syncthreads();
        int wbase = (wv == 0) ? 0 : swave[wv - 1];
        int run = x - tsum + wbase + sbase;
#pragma unroll
        for (int j = 0; j < 4; ++j) {
            run += v[j];
            int i = i0 + j;
            if (i < NN) row_ptr[i + 1] = run;
        }
        __syncthreads();
        if (t == 0) sbase += swave[15];
        __syncthreads();
    }
}

// ---------------------------------------------------------------- scatter
// R7: cursor array dropped — counts (dead after k_scan) decremented via
// atomicSub gives each edge a unique slot. Also writes 16 zero-pad entries
// past ep[EE] so k_edge_aggr's batch-16 reads never leave the buffer.
__global__ __launch_bounds__(256) void k_scatter(const int* __restrict__ src,
                                                 const int* __restrict__ dst,
                                                 const float* __restrict__ pos,
                                                 const int* __restrict__ row_ptr,
                                                 int* __restrict__ counts,
                                                 int2* __restrict__ ep) {
    int e = blockIdx.x * 256 + threadIdx.x;
    if (e < 16) ep[EE + e] = make_int2(0, 0);  // re-write pad every call (ws poisoned)
    if (e >= EE) return;
    int j = src[e], i = dst[e];
    int old = atomicSub(&counts[i], 1);
    int p = row_ptr[i] + old - 1;
    float dx = pos[2 * i] - pos[2 * j];
    float dy = pos[2 * i + 1] - pos[2 * j + 1];
    float dist = sqrtf(dx * dx + dy * dy);
    ep[p] = make_int2(j, __float_as_int(dist));
}

// ---------------------------------------------------------------- helpers
__device__ __forceinline__ float f4c(const float4& v, int kk) {
    switch (kk) {
        case 0: return v.x;
        case 1: return v.y;
        case 2: return v.z;
        default: return v.w;
    }
}

// ---------------------------------------------------------------- A/B GEMM (+ optional fused PairNorm on input)
template <bool NORM>
__global__ __launch_bounds__(256) void k_ab(const float* __restrict__ X,
                                            const float* __restrict__ gmu,
                                            const float* __restrict__ Wm,   // 129x64
                                            const float* __restrict__ bm,   // 64
                                            float* __restrict__ A,
                                            float* __restrict__ Bm) {
    __shared__ float sW[64 * 128];  // [k][c]
    __shared__ float sX[64 * 68];   // [r][k]
    const int tid = threadIdx.x;
    const int n0 = blockIdx.x * 64;

    for (int i4 = tid; i4 < 64 * 32; i4 += 256) {
        int k = i4 >> 5, cq = i4 & 31;
        float4 v = (cq < 16) ? ((const float4*)(Wm + k * 64))[cq]
                             : ((const float4*)(Wm + (64 + k) * 64))[cq - 16];
        ((float4*)sW)[i4] = v;
    }
    for (int i4 = tid; i4 < 64 * 16; i4 += 256) {
        int r = i4 >> 4, kq = i4 & 15;
        int n = n0 + r;
        float4 v = make_float4(0.f, 0.f, 0.f, 0.f);
        if (n < NN) v = *(const float4*)(X + n * DD + kq * 4);
        if (NORM) {
            float4 mu4 = *(const float4*)(gmu + kq * 4);
            float inv = gmu[64];
            v.x = (v.x - mu4.x) * inv;
            v.y = (v.y - mu4.y) * inv;
            v.z = (v.z - mu4.z) * inv;
            v.w = (v.w - mu4.w) * inv;
        }
        *(float4*)(&sX[r * 68 + kq * 4]) = v;
    }
    __syncthreads();

    const int rg = tid >> 4;
    const int cg = tid & 15;
    const int c0 = cg * 8;
    float acc[4][8];
#pragma unroll
    for (int cj = 0; cj < 8; ++cj) {
        float b = (c0 < 64) ? bm[c0 + cj] : 0.f;
        acc[0][cj] = b; acc[1][cj] = b; acc[2][cj] = b; acc[3][cj] = b;
    }
#pragma unroll 4
    for (int kq = 0; kq < 16; ++kq) {
        float4 x0 = *(const float4*)(&sX[(rg * 4 + 0) * 68 + kq * 4]);
        float4 x1 = *(const float4*)(&sX[(rg * 4 + 1) * 68 + kq * 4]);
        float4 x2 = *(const float4*)(&sX[(rg * 4 + 2) * 68 + kq * 4]);
        float4 x3 = *(const float4*)(&sX[(rg * 4 + 3) * 68 + kq * 4]);
#pragma unroll
        for (int kk = 0; kk < 4; ++kk) {
            const float* wr = &sW[(kq * 4 + kk) * 128 + c0];
            float4 w0 = *(const float4*)wr;
            float4 w1 = *(const float4*)(wr + 4);
            float wv[8] = {w0.x, w0.y, w0.z, w0.w, w1.x, w1.y, w1.z, w1.w};
            float a0 = f4c(x0, kk), a1 = f4c(x1, kk), a2 = f4c(x2, kk), a3 = f4c(x3, kk);
#pragma unroll
            for (int cj = 0; cj < 8; ++cj) {
                acc[0][cj] = fmaf(a0, wv[cj], acc[0][cj]);
                acc[1][cj] = fmaf(a1, wv[cj], acc[1][cj]);
                acc[2][cj] = fmaf(a2, wv[cj], acc[2][cj]);
                acc[3][cj] = fmaf(a3, wv[cj], acc[3][cj]);
            }
        }
    }
#pragma unroll
    for (int ri = 0; ri < 4; ++ri) {
        int n = n0 + rg * 4 + ri;
        if (n >= NN) continue;
        float4 o0 = make_float4(acc[ri][0], acc[ri][1], acc[ri][2], acc[ri][3]);
        float4 o1 = make_float4(acc[ri][4], acc[ri][5], acc[ri][6], acc[ri][7]);
        if (c0 < 64) {
            *(float4*)(A + n * DD + c0) = o0;
            *(float4*)(A + n * DD + c0 + 4) = o1;
        } else {
            *(float4*)(Bm + n * DD + (c0 - 64)) = o0;
            *(float4*)(Bm + n * DD + (c0 - 64) + 4) = o1;
        }
    }
}

// ---------------------------------------------------------------- edge aggregate, batch-16 fully in flight
// R7: one wave per node (50k waves — R6's fusion cut this 16x and regressed).
// One iteration issues 8 int4 ep-loads + 16 B-gathers before any use: ~97% of
// nodes (Poisson deg 10) take a single memory-latency round. Reads beyond the
// node's segment hit the next node's edges (valid, predicated off) or the
// 16-entry zero pad at ep[EE..EE+15].
__global__ __launch_bounds__(256) void k_edge_aggr(const float* __restrict__ A,
                                                   const float* __restrict__ B,
                                                   const float* __restrict__ w128,
                                                   const int* __restrict__ row_ptr,
                                                   const int2* __restrict__ ep,
                                                   float* __restrict__ aggr) {
    int i = (blockIdx.x * 256 + threadIdx.x) >> 6;
    int lane = threadIdx.x & 63;
    if (i >= NN) return;
    float w = w128[lane];
    float a = A[(size_t)i * DD + lane];
    int p0 = row_ptr[i], p1 = row_ptr[i + 1];
    float acc0 = 0.f, acc1 = 0.f, acc2 = 0.f, acc3 = 0.f;
    for (int p = p0; p < p1; p += 16) {
        int4 E[8];
#pragma unroll
        for (int q = 0; q < 8; ++q) E[q] = *(const int4*)(&ep[p + 2 * q]);
        float v[16];
#pragma unroll
        for (int q = 0; q < 8; ++q) {
            v[2 * q]     = B[(size_t)(unsigned)E[q].x * DD + lane];
            v[2 * q + 1] = B[(size_t)(unsigned)E[q].z * DD + lane];
        }
#pragma unroll
        for (int q = 0; q < 8; ++q) {
            float m0 = fmaxf(fmaf(__int_as_float(E[q].y), w, a) + v[2 * q], 0.f);
            float m1 = fmaxf(fmaf(__int_as_float(E[q].w), w, a) + v[2 * q + 1], 0.f);
            acc0 += (p + 2 * q < p1) ? m0 : 0.f;
            acc1 += (p + 2 * q + 1 < p1) ? m1 : 0.f;
            // rotate accumulators to shorten dependency chains
            float tmp = acc0; acc0 = acc2; acc2 = tmp;
            tmp = acc1; acc1 = acc3; acc3 = tmp;
        }
    }
    aggr[(size_t)i * DD + lane] = (acc0 + acc1) + (acc2 + acc3);
}

// ---------------------------------------------------------------- update GEMM + per-block stats partials (R5 version)
template <bool NORM>
__global__ __launch_bounds__(256) void k_upd(const float* __restrict__ h,
                                             const float* __restrict__ gmu,
                                             const float* __restrict__ ag,
                                             const float* __restrict__ Wu,  // 128x64
                                             const float* __restrict__ bu,  // 64
                                             float* __restrict__ hraw,
                                             float* __restrict__ part) {
    __shared__ float sW[64 * 64];
    __shared__ float sX[64 * 68];
    const int tid = threadIdx.x;
    const int n0 = blockIdx.x * 64;

    const int rg = tid >> 4;
    const int cg = tid & 15;
    const int c0 = cg * 4;
    float acc[4][4];
#pragma unroll
    for (int cj = 0; cj < 4; ++cj) {
        float b = bu[c0 + cj];
        acc[0][cj] = b; acc[1][cj] = b; acc[2][cj] = b; acc[3][cj] = b;
    }
#pragma unroll 1
    for (int half = 0; half < 2; ++half) {
        const float* X = half ? ag : h;
        const float* W = Wu + half * 64 * 64;
        if (half) __syncthreads();
        for (int i4 = tid; i4 < 64 * 16; i4 += 256)
            ((float4*)sW)[i4] = ((const float4*)W)[i4];
        for (int i4 = tid; i4 < 64 * 16; i4 += 256) {
            int r = i4 >> 4, kq = i4 & 15;
            int n = n0 + r;
            float4 v = make_float4(0.f, 0.f, 0.f, 0.f);
            if (n < NN) v = *(const float4*)(X + (size_t)n * DD + kq * 4);
            if (NORM && half == 0) {
                float4 mu4 = *(const float4*)(gmu + kq * 4);
                float inv = gmu[64];
                v.x = (v.x - mu4.x) * inv;
                v.y = (v.y - mu4.y) * inv;
                v.z = (v.z - mu4.z) * inv;
                v.w = (v.w - mu4.w) * inv;
            }
            *(float4*)(&sX[r * 68 + kq * 4]) = v;
        }
        __syncthreads();
#pragma unroll 4
        for (int kq = 0; kq < 16; ++kq) {
            float4 x0 = *(const float4*)(&sX[(rg * 4 + 0) * 68 + kq * 4]);
            float4 x1 = *(const float4*)(&sX[(rg * 4 + 1) * 68 + kq * 4]);
            float4 x2 = *(const float4*)(&sX[(rg * 4 + 2) * 68 + kq * 4]);
            float4 x3 = *(const float4*)(&sX[(rg * 4 + 3) * 68 + kq * 4]);
#pragma unroll
            for (int kk = 0; kk < 4; ++kk) {
                float4 wv4 = *(const float4*)(&sW[(kq * 4 + kk) * 64 + c0]);
                float wvv[4] = {wv4.x, wv4.y, wv4.z, wv4.w};
                float b0 = f4c(x0, kk), b1 = f4c(x1, kk), b2 = f4c(x2, kk), b3 = f4c(x3, kk);
#pragma unroll
                for (int cj = 0; cj < 4; ++cj) {
                    acc[0][cj] = fmaf(b0, wvv[cj], acc[0][cj]);
                    acc[1][cj] = fmaf(b1, wvv[cj], acc[1][cj]);
                    acc[2][cj] = fmaf(b2, wvv[cj], acc[2][cj]);
                    acc[3][cj] = fmaf(b3, wvv[cj], acc[3][cj]);
                }
            }
        }
    }
    float lsq = 0.f;
    float4 csum = make_float4(0.f, 0.f, 0.f, 0.f);
#pragma unroll
    for (int ri = 0; ri < 4; ++ri) {
        int n = n0 + rg * 4 + ri;
        if (n >= NN) continue;
        float r0 = fmaxf(acc[ri][0], 0.f);
        float r1 = fmaxf(acc[ri][1], 0.f);
        float r2 = fmaxf(acc[ri][2], 0.f);
        float r3 = fmaxf(acc[ri][3], 0.f);
        *(float4*)(hraw + (size_t)n * DD + c0) = make_float4(r0, r1, r2, r3);
        lsq += r0 * r0 + r1 * r1 + r2 * r2 + r3 * r3;
        csum.x += r0; csum.y += r1; csum.z += r2; csum.w += r3;
    }
    __syncthreads();
    *(float4*)(&sX[rg * 68 + c0]) = csum;
#pragma unroll
    for (int off = 32; off > 0; off >>= 1) lsq += __shfl_down(lsq, off);
    if ((tid & 63) == 0) part[blockIdx.x * 68 + 64 + (tid >> 6)] = lsq;
    __syncthreads();
    if (tid < 64) {
        float s = 0.f;
#pragma unroll
        for (int rr = 0; rr < 16; ++rr) s += sX[rr * 68 + tid];
        part[blockIdx.x * 68 + tid] = s;
    }
}

// ---------------------------------------------------------------- pairnorm stats finalize (reduce partials)
__global__ __launch_bounds__(1024) void k_stats(const float* __restrict__ part,
                                                float* __restrict__ gmu) {
    __shared__ float scol[16][64];
    __shared__ float sq[16][4];
    __shared__ float sQ;
    int t = threadIdx.x;
    int d = t & 63, c = t >> 6;
    float s = 0.f, q = 0.f;
    for (int b = c; b < UPD_BLOCKS; b += 16) {
        s += part[b * 68 + d];
        if (d < 4) q += part[b * 68 + 64 + d];
    }
    scol[c][d] = s;
    if (d < 4) sq[c][d] = q;
    __syncthreads();
    if (t == 0) {
        float Q = 0.f;
#pragma unroll
        for (int cc = 0; cc < 16; ++cc)
            Q += sq[cc][0] + sq[cc][1] + sq[cc][2] + sq[cc][3];
        sQ = Q;
    }
    __syncthreads();
    if (t < 64) {
        float colsum = 0.f;
#pragma unroll
        for (int cc = 0; cc < 16; ++cc) colsum += scol[cc][t];
        float mu = colsum * (1.f / NN);
        gmu[t] = mu;
        float v = mu * mu;
#pragma unroll
        for (int off = 32; off > 0; off >>= 1) v += __shfl_down(v, off);
        if (t == 0) {
            float denom = sqrtf(1e-5f + sQ * (1.f / NN) - v);
            gmu[64] = 1.f / denom;
        }
    }
}

// ---------------------------------------------------------------- pool: 4 blocks/graph -> partial maxes
__global__ __launch_bounds__(256) void k_pool(const float* __restrict__ h,
                                              float* __restrict__ hg4) {
    __shared__ float sm[4][DD];
    int g = blockIdx.x >> 2, q = blockIdx.x & 3;
    int wv = threadIdx.x >> 6, lane = threadIdx.x & 63;
    int base = g * NPG + q * (NPG / 4);
    float m = -3.0e38f;
    for (int n = base + wv; n < base + NPG / 4; n += 4)
        m = fmaxf(m, h[(size_t)n * DD + lane]);
    sm[wv][lane] = m;
    __syncthreads();
    if (wv == 0) {
        m = fmaxf(fmaxf(sm[0][lane], sm[1][lane]), fmaxf(sm[2][lane], sm[3][lane]));
        hg4[(size_t)blockIdx.x * DD + lane] = m;
    }
}

// ---------------------------------------------------------------- head MLP (+ fused final norm)
__global__ __launch_bounds__(64) void k_head(const float* __restrict__ hg4,
                                             const float* __restrict__ gmu,
                                             const float* __restrict__ W1,
                                             const float* __restrict__ b1,
                                             const float* __restrict__ W2,
                                             const float* __restrict__ b2,
                                             float* __restrict__ out) {
    __shared__ float shg[DD];
    __shared__ float st[DD];
    int g = blockIdx.x, d = threadIdx.x;
    float m = fmaxf(fmaxf(hg4[(g * 4 + 0) * DD + d], hg4[(g * 4 + 1) * DD + d]),
                    fmaxf(hg4[(g * 4 + 2) * DD + d], hg4[(g * 4 + 3) * DD + d]));
    shg[d] = (m - gmu[d]) * gmu[64];
    __syncthreads();
    float acc = b1[d];
    for (int k = 0; k < DD; ++k) acc = fmaf(shg[k], W1[k * DD + d], acc);
    st[d] = fmaxf(acc, 0.f);
    __syncthreads();
    if (d < 2) {
        float o = b2[d];
        for (int k = 0; k < DD; ++k) o = fmaf(st[k], W2[k * 2 + d], o);
        out[g * 2 + d] = o;
    }
}

// ---------------------------------------------------------------- launch
extern "C" void kernel_launch(void* const* d_in, const int* in_sizes, int n_in,
                              void* d_out, int out_size, void* d_ws, size_t ws_size,
                              hipStream_t stream) {
    (void)in_sizes; (void)n_in; (void)out_size; (void)ws_size;
    const float* h_in = (const float*)d_in[0];
    const float* pos  = (const float*)d_in[1];
    const int*   eidx = (const int*)d_in[2];
    const float* Wemb = (const float*)d_in[4];
    const float* bemb = (const float*)d_in[5];
    const float* msgW = (const float*)d_in[6]; // 2 x 129 x 64
    const float* msgb = (const float*)d_in[7]; // 2 x 64
    const float* updW = (const float*)d_in[8]; // 2 x 128 x 64
    const float* updb = (const float*)d_in[9]; // 2 x 64
    const float* W1   = (const float*)d_in[10];
    const float* b1   = (const float*)d_in[11];
    const float* W2   = (const float*)d_in[12];
    const float* b2   = (const float*)d_in[13];
    float* out = (float*)d_out;

    float* hbuf    = (float*)d_ws;            // N*64
    float* Abuf    = hbuf + NN * DD;          // N*64
    float* Bbuf    = Abuf + NN * DD;          // N*64
    float* aggr    = Bbuf + NN * DD;          // N*64
    float* gmu0    = aggr + NN * DD;          // 66
    float* gmu1    = gmu0 + 66;               // 66
    float* hg4     = gmu1 + 66;               // 200*64
    int2*  ep      = (int2*)(hg4 + 4 * GG * DD);  // E + 16 pad
    int* counts    = (int*)(ep + EE + 16);    // N   -- zeroed
    int* row_ptr   = counts + NN;             // N+1
    float* partials = (float*)(row_ptr + NN + 2); // UPD_BLOCKS*68

    const int* src = eidx;
    const int* dst = eidx + EE;

    hipMemsetAsync(counts, 0, NN * sizeof(int), stream);

    k_embed_hist<<<EMB_BLOCKS + HIST_BLOCKS, 256, 0, stream>>>(h_in, Wemb, bemb, hbuf,
                                                               dst, counts);
    k_scan<<<1, 1024, 0, stream>>>(counts, row_ptr);
    k_scatter<<<HIST_BLOCKS, 256, 0, stream>>>(src, dst, pos, row_ptr, counts, ep);

    // ---- layer 0: h=hbuf -> A=Abuf,B=Bbuf -> aggr -> hraw=Abuf
    {
        const float* Wm = msgW;
        k_ab<false><<<UPD_BLOCKS, 256, 0, stream>>>(hbuf, nullptr, Wm, msgb,
                                                    Abuf, Bbuf);
        k_edge_aggr<<<(NN + 3) / 4, 256, 0, stream>>>(Abuf, Bbuf, Wm + 128 * DD,
                                                      row_ptr, ep, aggr);
        k_upd<false><<<UPD_BLOCKS, 256, 0, stream>>>(hbuf, nullptr, aggr, updW,
                                                     updb, Abuf, partials);
        k_stats<<<1, 1024, 0, stream>>>(partials, gmu0);
    }
    // ---- layer 1: h=Abuf(+gmu0) -> A=hbuf,B=Bbuf -> aggr -> hraw=Bbuf
    {
        const float* Wm = msgW + 129 * DD;
        k_ab<true><<<UPD_BLOCKS, 256, 0, stream>>>(Abuf, gmu0, Wm, msgb + DD,
                                                   hbuf, Bbuf);
        k_edge_aggr<<<(NN + 3) / 4, 256, 0, stream>>>(hbuf, Bbuf, Wm + 128 * DD,
                                                      row_ptr, ep, aggr);
        k_upd<true><<<UPD_BLOCKS, 256, 0, stream>>>(Abuf, gmu0, aggr,
                                                    updW + 128 * DD, updb + DD,
                                                    Bbuf, partials);
        k_stats<<<1, 1024, 0, stream>>>(partials, gmu1);
    }

    k_pool<<<4 * GG, 256, 0, stream>>>(Bbuf, hg4);
    k_head<<<GG, 64, 0, stream>>>(hg4, gmu1, W1, b1, W2, b2, out);
}